// Round 19
// baseline (199.918 us; speedup 1.0000x reference)
//
#include <hip/hip_runtime.h>
#include <cmath>
#include <complex>

// Problem constants
constexpr int TT  = 50;            // time length
constexpr int NB  = 50;            // batch
constexpr int NC  = 4096;          // channels
constexpr int NCH = NB * NC;       // 204800 independent series
constexpr int PAD = 49;
constexpr int EXT = TT + 2 * PAD;  // 148
constexpr int CT  = 16;            // channel tile per block (block = CT x NB = 800 thr)

struct Coefs {
    double b0[2][2], b1[2][2], b2[2][2], a1[2][2], a2[2][2];
    double zi0[2][2], zi1[2][2];
};

// ---------------- Setup kernel: build the 2x50x50 filtfilt+demean matrix -----------
// Mt[(band*TT + k)*TT + t] = d y[t] / d x[k] (y demeaned over t), double precision.
// One block per band, thread j = basis column. Round-7 rewrite (verified r8-r18):
// analytic forward input (write-only forward pass), fused biquad sections
// (bit-identical dataflow), unroll-4 backward so ds_reads prefetch ahead.
__global__ void __launch_bounds__(64) build_M(float* __restrict__ Mt, Coefs cf) {
    __shared__ double e[EXT][TT];   // 148*50*8 = 59.2 KB
    const int band = blockIdx.x;
    const int j = threadIdx.x;
    if (j >= TT) return;

    const double b0a = cf.b0[band][0], b1a = cf.b1[band][0], b2a = cf.b2[band][0];
    const double a1a = cf.a1[band][0], a2a = cf.a2[band][0];
    const double b0b = cf.b0[band][1], b1b = cf.b1[band][1], b2b = cf.b2[band][1];
    const double a1b = cf.a1[band][1], a2b = cf.a2[band][1];

    // ext[0] = 2*x[0] - x[PAD]  (basis: delta at j)
    const double x0 = (j == 0 ? 2.0 : 0.0) - (j == PAD ? 1.0 : 0.0);

    double za0 = cf.zi0[band][0] * x0, za1 = cf.zi1[band][0] * x0;
    double zb0 = cf.zi0[band][1] * x0, zb1 = cf.zi1[band][1] * x0;

    double ylast = 0.0;
#pragma unroll
    for (int i = 0; i < EXT; ++i) {
        double xt;
        if (i < PAD) {                       // left odd-extension
            xt = (j == 0 ? 2.0 : 0.0) - (j == (PAD - i) ? 1.0 : 0.0);
        } else if (i < PAD + TT) {           // body: delta
            xt = (j == (i - PAD) ? 1.0 : 0.0);
        } else {                             // right odd-extension
            xt = (j == TT - 1 ? 2.0 : 0.0) - (j == (2 * TT - 2 + PAD - i) ? 1.0 : 0.0);
        }
        const double y0 = b0a * xt + za0;    // section 0
        za0 = b1a * xt + za1 - a1a * y0;
        za1 = b2a * xt - a2a * y0;
        const double y1 = b0b * y0 + zb0;    // section 1 (fused, in-register)
        zb0 = b1b * y0 + zb1 - a1b * y1;
        zb1 = b2b * y0 - a2b * y1;
        e[i][j] = y1;                        // write-only: no LDS read in this pass
        ylast = y1;
    }

    // backward pass over the reversed sequence; zi scaled by its first sample = ylast
    za0 = cf.zi0[band][0] * ylast; za1 = cf.zi1[band][0] * ylast;
    zb0 = cf.zi0[band][1] * ylast; zb1 = cf.zi1[band][1] * ylast;
#pragma unroll 4
    for (int m = 0; m < EXT; ++m) {
        const int i = EXT - 1 - m;
        const double xt = e[i][j];           // independent addr -> prefetches under unroll
        const double y0 = b0a * xt + za0;
        za0 = b1a * xt + za1 - a1a * y0;
        za1 = b2a * xt - a2a * y0;
        const double y1 = b0b * y0 + zb0;
        zb0 = b1b * y0 + zb1 - a1b * y1;
        zb1 = b2b * y0 - a2b * y1;
        e[i][j] = y1;
    }

    // slice [PAD, PAD+TT) and fold the demean over t (ascending -- verified order)
    double mean = 0.0;
#pragma unroll
    for (int t = 0; t < TT; ++t) mean += e[PAD + t][j];
    mean *= (1.0 / TT);
#pragma unroll
    for (int t = 0; t < TT; ++t)
        Mt[(band * TT + j) * TT + t] = (float)(e[PAD + t][j] - mean);
}

// ---------------- Fused DUAL-BAND GEMV + stats + normalize --------------------------
// Block = (CT=16 ch) x (all NB=50 b) = 800 threads. ROUND-18 POST-MORTEM: CT=8 was a
// 2x regression -- 32B wave segments amplified FETCH to 160MB (HBM line = 64-128B;
// the other half of each line belongs to a block on another XCD) and halved VALUBusy.
// CT=16 (64B segments, WRITE exactly ideal in r16/r17) is the verified floor. Occupancy
// is stuck at ~28% regardless of attrs (r17: (1,7) changed nothing) -> stop chasing
// TLP; raise PER-WAVE issue work instead:
//
// BAND FUSION (both bands per thread): each 5-load x group now feeds 500 FMAs
// (~1000 cyc of issue -- self-covering at 3 waves/SIMD), x is fetched ONCE
// (FETCH 80 -> ~42MB), grid halves to 256 blocks (one pass, not two). De-risked vs
// the r3/r5 spill disaster by two measured facts: f[50] lives in the unified AGPR
// file at VGPR_Count=36 (r16/r17), so f0+f1 ~ 36 VGPR + 100 AGPR ~= 136 vs the 128
// budget (800-thr block -> 4 waves/SIMD -> 512/4). TIGHT: WRITE_SIZE is the spill
// verdict (> 95MB -> revert to r17 single-band, 58us).
// Numerics byte-identical per band: same fmaf chains (k asc, t asc), same mu/ss
// order, same LDS-quirk epilogue (stats indexed by TIME position t = batch row t).
__global__ __launch_bounds__(CT * NB) __attribute__((amdgpu_waves_per_eu(1, 4)))
void fused_bn(const float* __restrict__ x, const float* __restrict__ Mt,
              float* __restrict__ out) {
    const int tx = threadIdx.x;                 // channel within tile
    const int b  = threadIdx.y;                 // batch
    const int c  = blockIdx.x * CT + tx;
    const int i  = b * NC + c;                  // column index into [B,C] plane

    __shared__ float sm_mu [2][NB][CT];
    __shared__ float sm_inv[2][NB][CT];

    const float* __restrict__ M0   = Mt;
    const float* __restrict__ M1   = Mt + TT * TT;
    const float* __restrict__ xcol = x + i;

    float f0[TT], f1[TT];
#pragma unroll
    for (int t = 0; t < TT; ++t) { f0[t] = 0.f; f1[t] = 0.f; }

    // unroll-5 groups: 5 independent x loads hoist to the top of each group, then
    // 500 FMAs (both bands) cover their latency. M rows are wave-uniform -> s_load
    // broadcast. Per-band chain order (k asc, t asc) identical to verified kernels.
#pragma unroll 5
    for (int k = 0; k < TT; ++k) {
        const float xk = xcol[(size_t)k * NCH];
        const float* __restrict__ r0 = M0 + k * TT;
#pragma unroll
        for (int t = 0; t < TT; ++t) f0[t] = fmaf(r0[t], xk, f0[t]);
        const float* __restrict__ r1 = M1 + k * TT;
#pragma unroll
        for (int t = 0; t < TT; ++t) f1[t] = fmaf(r1[t], xk, f1[t]);
    }

    // ddof=1 std about the actual mean (matches np.std); same op order as verified.
    {
        float mu = 0.f;
#pragma unroll
        for (int t = 0; t < TT; ++t) mu += f0[t];
        mu *= (1.0f / TT);
        float ss = 0.f;
#pragma unroll
        for (int t = 0; t < TT; ++t) {
            const float h = f0[t] - mu;
            ss = fmaf(h, h, ss);
        }
        sm_mu [0][b][tx] = mu;
        sm_inv[0][b][tx] = 1.0f / sqrtf(ss * (1.0f / (TT - 1)));
    }
    {
        float mu = 0.f;
#pragma unroll
        for (int t = 0; t < TT; ++t) mu += f1[t];
        mu *= (1.0f / TT);
        float ss = 0.f;
#pragma unroll
        for (int t = 0; t < TT; ++t) {
            const float h = f1[t] - mu;
            ss = fmaf(h, h, ss);
        }
        sm_mu [1][b][tx] = mu;
        sm_inv[1][b][tx] = 1.0f / sqrtf(ss * (1.0f / (TT - 1)));
    }
    __syncthreads();   // all stats of this c-tile (both bands) visible block-wide

    // normalize in-register f with row-t stats (THE QUIRK) and store out
#pragma unroll
    for (int t = 0; t < TT; ++t) {
        const float v = (f0[t] - sm_mu[0][t][tx]) * sm_inv[0][t][tx];
        out[(size_t)t * NCH + i] = v;
    }
#pragma unroll
    for (int t = 0; t < TT; ++t) {
        const float v = (f1[t] - sm_mu[1][t][tx]) * sm_inv[1][t][tx];
        out[(size_t)(TT + t) * NCH + i] = v;
    }
}

// ---------------- Host: Butterworth bandpass SOS + zi (reference-exact, double) ----
static Coefs make_coefs() {
    Coefs cf;
    const double bands[2][2] = {{0.05, 0.15}, {0.2, 0.4}};
    const int n = 2;  // ORDER
    for (int bd = 0; bd < 2; ++bd) {
        const double fs = 2.0;
        const double w1 = bands[bd][0], w2 = bands[bd][1];
        const double warped0 = 2.0 * fs * std::tan(M_PI * w1 / fs);
        const double warped1 = 2.0 * fs * std::tan(M_PI * w2 / fs);
        const double bw = warped1 - warped0;
        const double wo = std::sqrt(warped0 * warped1);
        std::complex<double> p_bp[4];
        for (int k = 1; k <= n; ++k) {
            std::complex<double> p = -std::exp(std::complex<double>(0.0, M_PI * (2 * k - 1) / (2.0 * n)));
            std::complex<double> plp = p * (bw / 2.0);
            std::complex<double> disc = std::sqrt(plp * plp - std::complex<double>(wo * wo, 0.0));
            p_bp[k - 1] = plp + disc;
            p_bp[n + k - 1] = plp - disc;
        }
        const double fs2 = 2.0 * fs;
        std::complex<double> prod(1.0, 0.0);
        for (int i = 0; i < 2 * n; ++i) prod *= (fs2 - p_bp[i]);
        const double gain = std::pow(bw, n) * std::pow(fs2, n) / prod.real();
        std::complex<double> p_d[4];
        for (int i = 0; i < 2 * n; ++i) p_d[i] = (fs2 + p_bp[i]) / (fs2 - p_bp[i]);
        double sos[2][6];
        int cnt = 0;
        for (int i = 0; i < 2 * n; ++i) {
            if (p_d[i].imag() > 0) {
                const double g = (cnt == 0) ? gain : 1.0;
                sos[cnt][0] = g;
                sos[cnt][1] = 0.0;
                sos[cnt][2] = -g;
                sos[cnt][3] = 1.0;
                sos[cnt][4] = -2.0 * p_d[i].real();
                sos[cnt][5] = std::norm(p_d[i]);
                ++cnt;
            }
        }
        double scale = 1.0;
        for (int s = 0; s < 2; ++s) {
            const double b0 = sos[s][0], b1 = sos[s][1], b2 = sos[s][2];
            const double a1 = sos[s][4], a2 = sos[s][5];
            const double B0 = b1 - a1 * b0, B1 = b2 - a2 * b0;
            const double det = 1.0 + a1 + a2;
            cf.b0[bd][s] = b0; cf.b1[bd][s] = b1; cf.b2[bd][s] = b2;
            cf.a1[bd][s] = a1; cf.a2[bd][s] = a2;
            cf.zi0[bd][s] = scale * (B0 + B1) / det;
            cf.zi1[bd][s] = scale * ((1.0 + a1) * B1 - a2 * B0) / det;
            scale *= (b0 + b1 + b2) / (1.0 + a1 + a2);
        }
    }
    return cf;
}

extern "C" void kernel_launch(void* const* d_in, const int* in_sizes, int n_in,
                              void* d_out, int out_size, void* d_ws, size_t ws_size,
                              hipStream_t stream) {
    const float* x = (const float*)d_in[0];
    float* out = (float*)d_out;
    float* Mt = (float*)d_ws;  // 2*50*50 floats = 20 KB

    const Coefs cf = make_coefs();
    build_M<<<dim3(2), dim3(64), 0, stream>>>(Mt, cf);
    fused_bn<<<dim3(NC / CT), dim3(CT, NB), 0, stream>>>(x, Mt, out);
}